// Round 3
// baseline (231.319 us; speedup 1.0000x reference)
//
#include <hip/hip_runtime.h>
#include <hip/hip_bf16.h>

// Non-local block, algebraically collapsed to out_b = x_b + A'_b x_b + bias'_b,
// A'_b = (U G_b V + u0 (V^T s_b)^T + (U s_b + N u0) tpb^T)/N,  G_b = x_b x_b^T.
// 4 launches: initprep -> gram(+rowsum+semaphore reduce) -> qa(fused) -> out.

#define CC   256
#define NSP  4096
#define NB   4
#define KSPLIT 16

typedef __attribute__((ext_vector_type(8))) short bf16x8;
typedef __attribute__((ext_vector_type(4))) float f32x4;

// ---------------- workspace layout ----------------
// fp32 region (float offsets from ws base)
#define F_P    0                         // [16][4][256][256] gram partials
#define F_CTR  4194304                   // [16] int tickets
#define F_U    4456448                   // [256][256]
#define F_VT   4521984                   // [256][256]  VT[i][j] = V[j][i]
#define F_S    4587520                   // [4][256]
#define F_U0   4588544                   // [256]
#define F_WTB  4588800                   // [256]
#define F_TPB  4589056                   // [256]
#define F_C0   4589312                   // [1]
#define F_BIAS 4589568                   // [4][256]
#define F_END  4590592
// bf16 region (ushort offsets from (ws + F_END floats))
#define H_XH   0                         // [4][256][4096] bf16 x
#define H_XT   4194304                   // [4][4096][256] bf16 x^T
#define H_GH   8388608                   // [4][256][256]
#define H_UH   8650752                   // [256][256]
#define H_VHT  8716288                   // [256][256]
#define H_AH   9043968                   // [4][256][256]

__device__ __forceinline__ unsigned short f2bf(float f) {
  __hip_bfloat16 h = __float2bfloat16(f);
  return __builtin_bit_cast(unsigned short, h);
}

__device__ __forceinline__ float bf2f(unsigned short u) {
  unsigned v = ((unsigned)u) << 16;
  return __builtin_bit_cast(float, v);
}

__device__ __forceinline__ uint4 pack8(const unsigned short* h) {
  uint4 u;
  u.x = (unsigned)h[0] | ((unsigned)h[1] << 16);
  u.y = (unsigned)h[2] | ((unsigned)h[3] << 16);
  u.z = (unsigned)h[4] | ((unsigned)h[5] << 16);
  u.w = (unsigned)h[6] | ((unsigned)h[7] << 16);
  return u;
}

// Wave computes C[64x64] += A[64xK] * B^T[64xK] (both row-major, K contiguous).
__device__ __forceinline__ void wave_gemm_bt(const unsigned short* __restrict__ A, int pitchA,
                                             const unsigned short* __restrict__ B, int pitchB,
                                             int K, int lane, f32x4 acc[4][4]) {
  int lm = lane & 15, lq = lane >> 4;
  const unsigned short* ap[4];
  const unsigned short* bp[4];
#pragma unroll
  for (int i = 0; i < 4; ++i) {
    ap[i] = A + (size_t)(i * 16 + lm) * pitchA + lq * 8;
    bp[i] = B + (size_t)(i * 16 + lm) * pitchB + lq * 8;
  }
  bf16x8 a0[4], b0[4];
#pragma unroll
  for (int i = 0; i < 4; ++i) {
    a0[i] = *(const bf16x8*)(ap[i]);
    b0[i] = *(const bf16x8*)(bp[i]);
  }
  for (int k = 32; k < K; k += 32) {
    bf16x8 a1[4], b1[4];
#pragma unroll
    for (int i = 0; i < 4; ++i) {
      a1[i] = *(const bf16x8*)(ap[i] + k);
      b1[i] = *(const bf16x8*)(bp[i] + k);
    }
#pragma unroll
    for (int mi = 0; mi < 4; ++mi)
#pragma unroll
      for (int ni = 0; ni < 4; ++ni)
        acc[mi][ni] = __builtin_amdgcn_mfma_f32_16x16x32_bf16(a0[mi], b0[ni], acc[mi][ni], 0, 0, 0);
#pragma unroll
    for (int i = 0; i < 4; ++i) { a0[i] = a1[i]; b0[i] = b1[i]; }
  }
#pragma unroll
  for (int mi = 0; mi < 4; ++mi)
#pragma unroll
    for (int ni = 0; ni < 4; ++ni)
      acc[mi][ni] = __builtin_amdgcn_mfma_f32_16x16x32_bf16(a0[mi], b0[ni], acc[mi][ni], 0, 0, 0);
}

// ---- merged init (weights) + prep (x cast/transpose) ----
__global__ __launch_bounds__(256) void k_initprep(
    const float* __restrict__ g_w, const float* __restrict__ g_b,
    const float* __restrict__ theta_w, const float* __restrict__ theta_b,
    const float* __restrict__ phi_w, const float* __restrict__ phi_b,
    const float* __restrict__ out_w, const float* __restrict__ x,
    float* __restrict__ wsf, unsigned short* __restrict__ wsh) {
  int bid = blockIdx.x, t = threadIdx.x;
  if (bid < 256) {                 // U[i][j] = sum_k out_w[i][k] g_w[k][j]
    int i = bid;
    float acc = 0.f;
    for (int k = 0; k < 128; ++k) acc = fmaf(out_w[i * 128 + k], g_w[k * CC + t], acc);
    wsf[F_U + i * CC + t] = acc;
    wsh[H_UH + i * CC + t] = f2bf(acc);
  } else if (bid < 512) {          // VT[i][j] = V[j][i] = sum_k theta_w[k][i] phi_w[k][j]
    int i = bid - 256;
    float acc = 0.f;
    for (int k = 0; k < 128; ++k) acc = fmaf(theta_w[k * CC + i], phi_w[k * CC + t], acc);
    wsf[F_VT + i * CC + t] = acc;
    wsh[H_VHT + i * CC + t] = f2bf(acc);
  } else if (bid == 512) {         // vectors + c0 + ticket zero
    float a0 = 0.f, a1 = 0.f, a2 = 0.f;
    for (int k = 0; k < 128; ++k) {
      a0 = fmaf(out_w[t * 128 + k], g_b[k], a0);
      a1 = fmaf(phi_w[k * CC + t], theta_b[k], a1);
      a2 = fmaf(theta_w[k * CC + t], phi_b[k], a2);
    }
    wsf[F_U0 + t]  = a0;
    wsf[F_WTB + t] = a1;
    wsf[F_TPB + t] = a2;
    if (t == 0) {
      float c = 0.f;
      for (int k = 0; k < 128; ++k) c = fmaf(phi_b[k], theta_b[k], c);
      wsf[F_C0] = c;
    }
    if (t < 16) ((int*)(wsf + F_CTR))[t] = 0;
  } else {                         // prep: bf16 cast + 64x64 transpose
    __shared__ float T[64][65];
    int pb = bid - 513;
    int nt = pb & 63, ct = (pb >> 6) & 3, b = pb >> 8;
    int c0 = ct * 64, n0 = nt * 64;
    int r = t >> 2, j = t & 3;
    const float* xr = x + ((size_t)b * CC + c0 + r) * NSP + n0 + j * 16;
    float4 f0 = *(const float4*)(xr);
    float4 f1 = *(const float4*)(xr + 4);
    float4 f2 = *(const float4*)(xr + 8);
    float4 f3 = *(const float4*)(xr + 12);
    float v[16] = {f0.x, f0.y, f0.z, f0.w, f1.x, f1.y, f1.z, f1.w,
                   f2.x, f2.y, f2.z, f2.w, f3.x, f3.y, f3.z, f3.w};
    unsigned short hs[16];
#pragma unroll
    for (int i = 0; i < 16; ++i) hs[i] = f2bf(v[i]);
    size_t xo = ((size_t)b * CC + c0 + r) * NSP + n0 + j * 16;
    *(uint4*)(wsh + H_XH + xo)     = pack8(hs);
    *(uint4*)(wsh + H_XH + xo + 8) = pack8(hs + 8);
    *(float4*)&T[r][j * 16 + 0]  = f0;
    *(float4*)&T[r][j * 16 + 4]  = f1;
    *(float4*)&T[r][j * 16 + 8]  = f2;
    *(float4*)&T[r][j * 16 + 12] = f3;
    __syncthreads();
    int nr = t >> 2, j2 = t & 3;
    unsigned short o[16];
#pragma unroll
    for (int i = 0; i < 16; ++i) o[i] = f2bf(T[j2 * 16 + i][nr]);
    size_t to = ((size_t)b * NSP + n0 + nr) * CC + c0 + j2 * 16;
    *(uint4*)(wsh + H_XT + to)     = pack8(o);
    *(uint4*)(wsh + H_XT + to + 8) = pack8(o + 8);
  }
}

// ---- Gram split-K + in-kernel ticket reduce -> Gh bf16; plus rowsums ----
__global__ __launch_bounds__(256) void k_gram(const unsigned short* __restrict__ wsh,
                                              float* __restrict__ wsf,
                                              unsigned short* __restrict__ wshw) {
  int bid = blockIdx.x, t = threadIdx.x;
  if (bid < 256) {
    int ks = bid & 15, t4 = (bid >> 4) & 3, b = bid >> 6;
    int tm = t4 >> 1, tn = t4 & 1;
    int w = t >> 6, lane = t & 63;
    int wm = w >> 1, wn = w & 1;
    const unsigned short* xb = wsh + H_XH + (size_t)b * CC * NSP;
    const unsigned short* A = xb + (size_t)(tm * 128 + wm * 64) * NSP + ks * 256;
    const unsigned short* B = xb + (size_t)(tn * 128 + wn * 64) * NSP + ks * 256;
    f32x4 acc[4][4] = {};
    wave_gemm_bt(A, NSP, B, NSP, 256, lane, acc);
    float* P = wsf + F_P + (size_t)(ks * 4 + b) * 65536;
    int lm = lane & 15, lq = lane >> 4;
    int rb = tm * 128 + wm * 64, cb = tn * 128 + wn * 64;
#pragma unroll
    for (int mi = 0; mi < 4; ++mi)
#pragma unroll
      for (int rr = 0; rr < 4; ++rr) {
        int row = rb + mi * 16 + lq * 4 + rr;
#pragma unroll
        for (int ni = 0; ni < 4; ++ni)
          P[row * CC + cb + ni * 16 + lm] = acc[mi][ni][rr];
      }
    // ticket: last of the 16 split-K blocks reduces this (b, 128x128 tile)
    __threadfence();
    __syncthreads();
    __shared__ int oldc;
    if (t == 0) oldc = atomicAdd((int*)(wsf + F_CTR) + (b * 4 + t4), 1);
    __syncthreads();
    if (oldc == 15) {
      __threadfence();
      int rb2 = tm * 128, cb2 = tn * 128;
      for (int e = t; e < 16384; e += 256) {
        int r = e >> 7, cl = e & 127;
        const float* p = wsf + F_P + (size_t)b * 65536 + (size_t)(rb2 + r) * CC + cb2 + cl;
        float a = 0.f;
#pragma unroll
        for (int k2 = 0; k2 < KSPLIT; ++k2) a += p[(size_t)k2 * 262144];
        wshw[H_GH + (size_t)b * 65536 + (size_t)(rb2 + r) * CC + cb2 + cl] = f2bf(a);
      }
    }
  } else {                         // rowsums from bf16 x: bid 256..319
    int rid = bid - 256;
    int b = rid >> 4, rg = rid & 15;
    int row = rg * 16 + (t >> 4), sub = t & 15;
    const unsigned short* xr = wsh + H_XH + ((size_t)b * CC + row) * NSP + sub * 256;
    float s = 0.f;
    for (int q = 0; q < 256; q += 8) {
      bf16x8 v = *(const bf16x8*)(xr + q);
#pragma unroll
      for (int e = 0; e < 8; ++e) s += bf2f((unsigned short)v[e]);
    }
    s += __shfl_down(s, 8);
    s += __shfl_down(s, 4);
    s += __shfl_down(s, 2);
    s += __shfl_down(s, 1);
    if (sub == 0) wsf[F_S + b * CC + row] = s;
  }
}

// ---- fused: Q = Uh@Gh (LDS) then A' = Q@V + rank-1 + bias ----
__global__ __launch_bounds__(512) void k_qa(const float* __restrict__ wsf,
                                            unsigned short* __restrict__ wsh,
                                            const float* __restrict__ out_b,
                                            float* __restrict__ wsfw) {
  __shared__ unsigned short Qh[128][264];
  __shared__ float sL[256], vtsL[256], wtbL[256], tpbL[256];
  __shared__ float usnL[128], qrL[128], u0L[128], red[512];
  __shared__ float swS;
  int bid = blockIdx.x;
  int b = bid >> 1, tm = bid & 1;
  int t = threadIdx.x, w = t >> 6, lane = t & 63;
  int wr = w >> 2, wc = w & 3;
  int lm = lane & 15, lq = lane >> 4;
  const float inv = 1.0f / 4096.0f;

  if (t < 256) {
    sL[t]   = wsf[F_S + b * CC + t];
    wtbL[t] = wsf[F_WTB + t];
    tpbL[t] = wsf[F_TPB + t];
  }
  if (t < 128) u0L[t] = wsf[F_U0 + tm * 128 + t];
  __syncthreads();
  {  // vts[j] = dot(VT[j], s), 2 threads per j
    int j = t >> 1, half = t & 1;
    const float* vr = wsf + F_VT + (size_t)j * CC + half * 128;
    float p = 0.f;
    for (int k = 0; k < 128; ++k) p = fmaf(vr[k], sL[half * 128 + k], p);
    red[t] = p;
  }
  __syncthreads();
  if ((t & 1) == 0) vtsL[t >> 1] = red[t] + red[t + 1];
  __syncthreads();
  {  // usn[il] = dot(U[tm*128+il], s) + N*u0, 4 threads per il
    int il = t >> 2, q = t & 3;
    const float* ur = wsf + F_U + (size_t)(tm * 128 + il) * CC + q * 64;
    float p = 0.f;
    for (int k = 0; k < 64; ++k) p = fmaf(ur[k], sL[q * 64 + k], p);
    red[t] = p;
  }
  __syncthreads();
  if ((t & 3) == 0) {
    int il = t >> 2;
    usnL[il] = red[t] + red[t + 1] + red[t + 2] + red[t + 3] + 4096.0f * u0L[il];
  }
  __syncthreads();
  red[t] = (t < 256) ? sL[t] * wtbL[t] : 0.f;
  __syncthreads();
  for (int st = 256; st > 0; st >>= 1) {
    if (t < st) red[t] += red[t + st];
    __syncthreads();
  }
  if (t == 0) swS = red[0];

  // stage 1: Q[128,256] = Uh[tm rows] @ Gh  (G symmetric -> B^T = G rows)
  {
    const unsigned short* A1 = wsh + H_UH + (size_t)(tm * 128 + wr * 64) * CC;
    const unsigned short* B1 = wsh + H_GH + (size_t)b * 65536 + (size_t)(wc * 64) * CC;
    f32x4 acc[4][4] = {};
    wave_gemm_bt(A1, CC, B1, CC, 256, lane, acc);
#pragma unroll
    for (int mi = 0; mi < 4; ++mi)
#pragma unroll
      for (int rr = 0; rr < 4; ++rr) {
        int rl = wr * 64 + mi * 16 + lq * 4 + rr;
#pragma unroll
        for (int ni = 0; ni < 4; ++ni)
          Qh[rl][wc * 64 + ni * 16 + lm] = f2bf(acc[mi][ni][rr]);
      }
  }
  __syncthreads();
  {  // qr[il] = dot(Q[il], wtb), 4 threads per il
    int il = t >> 2, q = t & 3;
    float p = 0.f;
    for (int k = 0; k < 64; ++k) p = fmaf(bf2f(Qh[il][q * 64 + k]), wtbL[q * 64 + k], p);
    red[t] = p;
  }
  __syncthreads();
  if ((t & 3) == 0) qrL[t >> 2] = red[t] + red[t + 1] + red[t + 2] + red[t + 3];
  __syncthreads();
  float c0v = wsf[F_C0];
  if (t < 128) {
    int i = tm * 128 + t;
    wsfw[F_BIAS + b * CC + i] =
        (qrL[t] + u0L[t] * swS + usnL[t] * c0v) * inv + out_b[i];
  }

  // stage 2: A'[128,256] = Q @ V  (B^T = VT rows), + rank-1, -> bf16
  {
    const unsigned short* B2 = wsh + H_VHT + (size_t)(wc * 64) * CC;
    f32x4 acc[4][4] = {};
    for (int k0 = 0; k0 < 256; k0 += 32) {
      bf16x8 a[4], bb[4];
#pragma unroll
      for (int i = 0; i < 4; ++i) {
        a[i]  = *(const bf16x8*)(&Qh[wr * 64 + i * 16 + lm][lq * 8 + k0]);
        bb[i] = *(const bf16x8*)(B2 + (size_t)(i * 16 + lm) * CC + lq * 8 + k0);
      }
#pragma unroll
      for (int mi = 0; mi < 4; ++mi)
#pragma unroll
        for (int ni = 0; ni < 4; ++ni)
          acc[mi][ni] = __builtin_amdgcn_mfma_f32_16x16x32_bf16(a[mi], bb[ni], acc[mi][ni], 0, 0, 0);
    }
#pragma unroll
    for (int mi = 0; mi < 4; ++mi)
#pragma unroll
      for (int rr = 0; rr < 4; ++rr) {
        int rl = wr * 64 + mi * 16 + lq * 4 + rr;
        int gi = tm * 128 + rl;
        float u0i = u0L[rl];
        float usn = usnL[rl];
#pragma unroll
        for (int ni = 0; ni < 4; ++ni) {
          int gj = wc * 64 + ni * 16 + lm;
          float vv = (acc[mi][ni][rr] + u0i * vtsL[gj] + usn * tpbL[gj]) * inv;
          wsh[H_AH + (size_t)b * 65536 + (size_t)gi * CC + gj] = f2bf(vv);
        }
      }
  }
}

// ---- out = x + Ah @ x (via xT) + bias ----
__global__ __launch_bounds__(256) void k_out(const unsigned short* __restrict__ wsh,
                                             const float* __restrict__ wsf,
                                             const float* __restrict__ x,
                                             float* __restrict__ out) {
  int bid = blockIdx.x;
  int b = bid >> 6, r6 = bid & 63;
  int tm = r6 >> 5, tn = r6 & 31;
  int t = threadIdx.x, w = t >> 6, lane = t & 63;
  int wm = w >> 1, wn = w & 1;
  const unsigned short* A = wsh + H_AH + (size_t)b * 65536 + (size_t)(tm * 128 + wm * 64) * CC;
  const unsigned short* B = wsh + H_XT + ((size_t)b * NSP + tn * 128 + wn * 64) * CC;
  f32x4 acc[4][4] = {};
  wave_gemm_bt(A, CC, B, CC, 256, lane, acc);
  int lm = lane & 15, lq = lane >> 4;
  int rb = tm * 128 + wm * 64, cb = tn * 128 + wn * 64;
#pragma unroll
  for (int mi = 0; mi < 4; ++mi)
#pragma unroll
    for (int rr = 0; rr < 4; ++rr) {
      int row = rb + mi * 16 + lq * 4 + rr;
      float bi = wsf[F_BIAS + b * CC + row];
#pragma unroll
      for (int ni = 0; ni < 4; ++ni) {
        int col = cb + ni * 16 + lm;
        size_t off = ((size_t)b * CC + row) * NSP + col;
        out[off] = acc[mi][ni][rr] + x[off] + bi;
      }
    }
}

extern "C" void kernel_launch(void* const* d_in, const int* in_sizes, int n_in,
                              void* d_out, int out_size, void* d_ws, size_t ws_size,
                              hipStream_t stream) {
  const float* x       = (const float*)d_in[0];
  const float* g_w     = (const float*)d_in[1];
  const float* g_b     = (const float*)d_in[2];
  const float* theta_w = (const float*)d_in[3];
  const float* theta_b = (const float*)d_in[4];
  const float* phi_w   = (const float*)d_in[5];
  const float* phi_b   = (const float*)d_in[6];
  const float* out_w   = (const float*)d_in[7];
  const float* out_b   = (const float*)d_in[8];
  float* wsf = (float*)d_ws;
  unsigned short* wsh = (unsigned short*)(wsf + F_END);
  float* out = (float*)d_out;

  k_initprep<<<dim3(1537), dim3(256), 0, stream>>>(g_w, g_b, theta_w, theta_b,
                                                   phi_w, phi_b, out_w, x, wsf, wsh);
  k_gram<<<dim3(320), dim3(256), 0, stream>>>(wsh, wsf, wsh);
  k_qa<<<dim3(8), dim3(512), 0, stream>>>(wsf, wsh, out_b, wsf);
  k_out<<<dim3(256), dim3(256), 0, stream>>>(wsh, wsf, x, out);
}

// Round 4
// 169.607 us; speedup vs baseline: 1.3639x; 1.3639x over previous
//
#include <hip/hip_runtime.h>
#include <hip/hip_bf16.h>

// Non-local block, algebraically collapsed to out_b = x_b + A'_b x_b + bias'_b,
// A'_b = (U G_b V + u0 (V^T s_b)^T + (U s_b + N u0) tpb^T)/N,  G_b = x_b x_b^T.
// 5 launches: initprep -> gram(+rowsum) -> gsum -> qa(fused, Q in LDS) -> out.

#define CC   256
#define NSP  4096
#define NB   4
#define KSPLIT 8

typedef __attribute__((ext_vector_type(8))) short bf16x8;
typedef __attribute__((ext_vector_type(4))) float f32x4;

// ---------------- workspace layout ----------------
// fp32 region (float offsets from ws base)
#define F_P    0                         // [8][4][256][256] gram partials
#define F_U    4456448                   // [256][256]
#define F_VT   4521984                   // [256][256]  VT[i][j] = V[j][i]
#define F_S    4587520                   // [4][256]
#define F_U0   4588544                   // [256]
#define F_WTB  4588800                   // [256]
#define F_TPB  4589056                   // [256]
#define F_C0   4589312                   // [1]
#define F_BIAS 4589568                   // [4][256]
#define F_END  4590592
// bf16 region (ushort offsets from (ws + F_END floats))
#define H_XH   0                         // [4][256][4096] bf16 x
#define H_XT   4194304                   // [4][4096][256] bf16 x^T
#define H_GH   8388608                   // [4][256][256]
#define H_UH   8650752                   // [256][256]
#define H_VHT  8716288                   // [256][256]
#define H_AH   9043968                   // [4][256][256]

__device__ __forceinline__ unsigned short f2bf(float f) {
  __hip_bfloat16 h = __float2bfloat16(f);
  return __builtin_bit_cast(unsigned short, h);
}

__device__ __forceinline__ float bf2f(unsigned short u) {
  unsigned v = ((unsigned)u) << 16;
  return __builtin_bit_cast(float, v);
}

__device__ __forceinline__ uint4 pack8(const unsigned short* h) {
  uint4 u;
  u.x = (unsigned)h[0] | ((unsigned)h[1] << 16);
  u.y = (unsigned)h[2] | ((unsigned)h[3] << 16);
  u.z = (unsigned)h[4] | ((unsigned)h[5] << 16);
  u.w = (unsigned)h[6] | ((unsigned)h[7] << 16);
  return u;
}

// Wave computes C[64x64] += A[64xK] * B^T[64xK] (both row-major, K contiguous).
__device__ __forceinline__ void wave_gemm_bt(const unsigned short* __restrict__ A, int pitchA,
                                             const unsigned short* __restrict__ B, int pitchB,
                                             int K, int lane, f32x4 acc[4][4]) {
  int lm = lane & 15, lq = lane >> 4;
  const unsigned short* ap[4];
  const unsigned short* bp[4];
#pragma unroll
  for (int i = 0; i < 4; ++i) {
    ap[i] = A + (size_t)(i * 16 + lm) * pitchA + lq * 8;
    bp[i] = B + (size_t)(i * 16 + lm) * pitchB + lq * 8;
  }
  bf16x8 a0[4], b0[4];
#pragma unroll
  for (int i = 0; i < 4; ++i) {
    a0[i] = *(const bf16x8*)(ap[i]);
    b0[i] = *(const bf16x8*)(bp[i]);
  }
  for (int k = 32; k < K; k += 32) {
    bf16x8 a1[4], b1[4];
#pragma unroll
    for (int i = 0; i < 4; ++i) {
      a1[i] = *(const bf16x8*)(ap[i] + k);
      b1[i] = *(const bf16x8*)(bp[i] + k);
    }
#pragma unroll
    for (int mi = 0; mi < 4; ++mi)
#pragma unroll
      for (int ni = 0; ni < 4; ++ni)
        acc[mi][ni] = __builtin_amdgcn_mfma_f32_16x16x32_bf16(a0[mi], b0[ni], acc[mi][ni], 0, 0, 0);
#pragma unroll
    for (int i = 0; i < 4; ++i) { a0[i] = a1[i]; b0[i] = b1[i]; }
  }
#pragma unroll
  for (int mi = 0; mi < 4; ++mi)
#pragma unroll
    for (int ni = 0; ni < 4; ++ni)
      acc[mi][ni] = __builtin_amdgcn_mfma_f32_16x16x32_bf16(a0[mi], b0[ni], acc[mi][ni], 0, 0, 0);
}

// ---- merged init (weights) + prep (x cast/transpose) ----
__global__ __launch_bounds__(256) void k_initprep(
    const float* __restrict__ g_w, const float* __restrict__ g_b,
    const float* __restrict__ theta_w, const float* __restrict__ theta_b,
    const float* __restrict__ phi_w, const float* __restrict__ phi_b,
    const float* __restrict__ out_w, const float* __restrict__ x,
    float* __restrict__ wsf, unsigned short* __restrict__ wsh) {
  int bid = blockIdx.x, t = threadIdx.x;
  if (bid < 256) {                 // U[i][j] = sum_k out_w[i][k] g_w[k][j]
    int i = bid;
    float acc = 0.f;
    for (int k = 0; k < 128; ++k) acc = fmaf(out_w[i * 128 + k], g_w[k * CC + t], acc);
    wsf[F_U + i * CC + t] = acc;
    wsh[H_UH + i * CC + t] = f2bf(acc);
  } else if (bid < 512) {          // VT[i][j] = V[j][i] = sum_k theta_w[k][i] phi_w[k][j]
    int i = bid - 256;
    float acc = 0.f;
    for (int k = 0; k < 128; ++k) acc = fmaf(theta_w[k * CC + i], phi_w[k * CC + t], acc);
    wsf[F_VT + i * CC + t] = acc;
    wsh[H_VHT + i * CC + t] = f2bf(acc);
  } else if (bid == 512) {         // vectors + c0
    float a0 = 0.f, a1 = 0.f, a2 = 0.f;
    for (int k = 0; k < 128; ++k) {
      a0 = fmaf(out_w[t * 128 + k], g_b[k], a0);
      a1 = fmaf(phi_w[k * CC + t], theta_b[k], a1);
      a2 = fmaf(theta_w[k * CC + t], phi_b[k], a2);
    }
    wsf[F_U0 + t]  = a0;
    wsf[F_WTB + t] = a1;
    wsf[F_TPB + t] = a2;
    if (t == 0) {
      float c = 0.f;
      for (int k = 0; k < 128; ++k) c = fmaf(phi_b[k], theta_b[k], c);
      wsf[F_C0] = c;
    }
  } else {                         // prep: bf16 cast + 64x64 transpose
    __shared__ float T[64][65];
    int pb = bid - 513;
    int nt = pb & 63, ct = (pb >> 6) & 3, b = pb >> 8;
    int c0 = ct * 64, n0 = nt * 64;
    int r = t >> 2, j = t & 3;
    const float* xr = x + ((size_t)b * CC + c0 + r) * NSP + n0 + j * 16;
    float4 f0 = *(const float4*)(xr);
    float4 f1 = *(const float4*)(xr + 4);
    float4 f2 = *(const float4*)(xr + 8);
    float4 f3 = *(const float4*)(xr + 12);
    float v[16] = {f0.x, f0.y, f0.z, f0.w, f1.x, f1.y, f1.z, f1.w,
                   f2.x, f2.y, f2.z, f2.w, f3.x, f3.y, f3.z, f3.w};
    unsigned short hs[16];
#pragma unroll
    for (int i = 0; i < 16; ++i) hs[i] = f2bf(v[i]);
    size_t xo = ((size_t)b * CC + c0 + r) * NSP + n0 + j * 16;
    *(uint4*)(wsh + H_XH + xo)     = pack8(hs);
    *(uint4*)(wsh + H_XH + xo + 8) = pack8(hs + 8);
    *(float4*)&T[r][j * 16 + 0]  = f0;
    *(float4*)&T[r][j * 16 + 4]  = f1;
    *(float4*)&T[r][j * 16 + 8]  = f2;
    *(float4*)&T[r][j * 16 + 12] = f3;
    __syncthreads();
    int nr = t >> 2, j2 = t & 3;
    unsigned short o[16];
#pragma unroll
    for (int i = 0; i < 16; ++i) o[i] = f2bf(T[j2 * 16 + i][nr]);
    size_t to = ((size_t)b * NSP + n0 + nr) * CC + c0 + j2 * 16;
    *(uint4*)(wsh + H_XT + to)     = pack8(o);
    *(uint4*)(wsh + H_XT + to + 8) = pack8(o + 8);
  }
}

// ---- Gram split-K=8 partials + rowsums (no in-kernel reduce) ----
__global__ __launch_bounds__(256) void k_gram(const unsigned short* __restrict__ wsh,
                                              float* __restrict__ wsf) {
  int bid = blockIdx.x, t = threadIdx.x;
  if (bid < 128) {
    int ks = bid & 7, t4 = (bid >> 3) & 3, b = bid >> 5;
    int tm = t4 >> 1, tn = t4 & 1;
    int w = t >> 6, lane = t & 63;
    int wm = w >> 1, wn = w & 1;
    const unsigned short* xb = wsh + H_XH + (size_t)b * CC * NSP;
    const unsigned short* A = xb + (size_t)(tm * 128 + wm * 64) * NSP + ks * 512;
    const unsigned short* B = xb + (size_t)(tn * 128 + wn * 64) * NSP + ks * 512;
    f32x4 acc[4][4] = {};
    wave_gemm_bt(A, NSP, B, NSP, 512, lane, acc);
    float* P = wsf + F_P + (size_t)(ks * 4 + b) * 65536;
    int lm = lane & 15, lq = lane >> 4;
    int rb = tm * 128 + wm * 64, cb = tn * 128 + wn * 64;
#pragma unroll
    for (int mi = 0; mi < 4; ++mi)
#pragma unroll
      for (int rr = 0; rr < 4; ++rr) {
        int row = rb + mi * 16 + lq * 4 + rr;
#pragma unroll
        for (int ni = 0; ni < 4; ++ni)
          P[row * CC + cb + ni * 16 + lm] = acc[mi][ni][rr];
      }
  } else {                         // rowsums from bf16 x: bid 128..191
    int rid = bid - 128;
    int b = rid >> 4, rg = rid & 15;
    int row = rg * 16 + (t >> 4), sub = t & 15;
    const unsigned short* xr = wsh + H_XH + ((size_t)b * CC + row) * NSP + sub * 256;
    float s = 0.f;
    for (int q = 0; q < 256; q += 8) {
      bf16x8 v = *(const bf16x8*)(xr + q);
#pragma unroll
      for (int e = 0; e < 8; ++e) s += bf2f((unsigned short)v[e]);
    }
    s += __shfl_down(s, 8);
    s += __shfl_down(s, 4);
    s += __shfl_down(s, 2);
    s += __shfl_down(s, 1);
    if (sub == 0) wsf[F_S + b * CC + row] = s;
  }
}

// ---- reduce partials -> Gh bf16 (wide, vectorized) ----
__global__ __launch_bounds__(256) void k_gsum(const float* __restrict__ wsf,
                                              unsigned short* __restrict__ wsh) {
  int idx4 = (blockIdx.x * 256 + threadIdx.x) * 4;   // over 262144 els
  float4 a = {0.f, 0.f, 0.f, 0.f};
#pragma unroll
  for (int ks = 0; ks < KSPLIT; ++ks) {
    float4 p = *(const float4*)(wsf + F_P + (size_t)ks * 262144 + idx4);
    a.x += p.x; a.y += p.y; a.z += p.z; a.w += p.w;
  }
  uint2 o;
  o.x = (unsigned)f2bf(a.x) | ((unsigned)f2bf(a.y) << 16);
  o.y = (unsigned)f2bf(a.z) | ((unsigned)f2bf(a.w) << 16);
  *(uint2*)(wsh + H_GH + idx4) = o;
}

// ---- fused: Q = Uh@Gh (LDS) then A' = Q@V + rank-1 + bias ----
__global__ __launch_bounds__(512) void k_qa(const float* __restrict__ wsf,
                                            unsigned short* __restrict__ wsh,
                                            const float* __restrict__ out_b,
                                            float* __restrict__ wsfw) {
  __shared__ unsigned short Qh[128][264];
  __shared__ float sL[256], vtsL[256], wtbL[256], tpbL[256];
  __shared__ float usnL[128], qrL[128], u0L[128], red[512];
  __shared__ float swS;
  int bid = blockIdx.x;
  int b = bid >> 1, tm = bid & 1;
  int t = threadIdx.x, w = t >> 6, lane = t & 63;
  int wr = w >> 2, wc = w & 3;
  int lm = lane & 15, lq = lane >> 4;
  const float inv = 1.0f / 4096.0f;

  if (t < 256) {
    sL[t]   = wsf[F_S + b * CC + t];
    wtbL[t] = wsf[F_WTB + t];
    tpbL[t] = wsf[F_TPB + t];
  }
  if (t < 128) u0L[t] = wsf[F_U0 + tm * 128 + t];
  __syncthreads();
  {  // vts[j] = dot(VT[j], s), 2 threads per j
    int j = t >> 1, half = t & 1;
    const float* vr = wsf + F_VT + (size_t)j * CC + half * 128;
    float p = 0.f;
    for (int k = 0; k < 128; ++k) p = fmaf(vr[k], sL[half * 128 + k], p);
    red[t] = p;
  }
  __syncthreads();
  if ((t & 1) == 0) vtsL[t >> 1] = red[t] + red[t + 1];
  __syncthreads();
  {  // usn[il] = dot(U[tm*128+il], s) + N*u0, 4 threads per il
    int il = t >> 2, q = t & 3;
    const float* ur = wsf + F_U + (size_t)(tm * 128 + il) * CC + q * 64;
    float p = 0.f;
    for (int k = 0; k < 64; ++k) p = fmaf(ur[k], sL[q * 64 + k], p);
    red[t] = p;
  }
  __syncthreads();
  if ((t & 3) == 0) {
    int il = t >> 2;
    usnL[il] = red[t] + red[t + 1] + red[t + 2] + red[t + 3] + 4096.0f * u0L[il];
  }
  __syncthreads();
  red[t] = (t < 256) ? sL[t] * wtbL[t] : 0.f;
  __syncthreads();
  for (int st = 256; st > 0; st >>= 1) {
    if (t < st) red[t] += red[t + st];
    __syncthreads();
  }
  if (t == 0) swS = red[0];

  // stage 1: Q[128,256] = Uh[tm rows] @ Gh  (G symmetric -> B^T = G rows)
  {
    const unsigned short* A1 = wsh + H_UH + (size_t)(tm * 128 + wr * 64) * CC;
    const unsigned short* B1 = wsh + H_GH + (size_t)b * 65536 + (size_t)(wc * 64) * CC;
    f32x4 acc[4][4] = {};
    wave_gemm_bt(A1, CC, B1, CC, 256, lane, acc);
#pragma unroll
    for (int mi = 0; mi < 4; ++mi)
#pragma unroll
      for (int rr = 0; rr < 4; ++rr) {
        int rl = wr * 64 + mi * 16 + lq * 4 + rr;
#pragma unroll
        for (int ni = 0; ni < 4; ++ni)
          Qh[rl][wc * 64 + ni * 16 + lm] = f2bf(acc[mi][ni][rr]);
      }
  }
  __syncthreads();
  {  // qr[il] = dot(Q[il], wtb), 4 threads per il
    int il = t >> 2, q = t & 3;
    float p = 0.f;
    for (int k = 0; k < 64; ++k) p = fmaf(bf2f(Qh[il][q * 64 + k]), wtbL[q * 64 + k], p);
    red[t] = p;
  }
  __syncthreads();
  if ((t & 3) == 0) qrL[t >> 2] = red[t] + red[t + 1] + red[t + 2] + red[t + 3];
  __syncthreads();
  float c0v = wsf[F_C0];
  if (t < 128) {
    int i = tm * 128 + t;
    wsfw[F_BIAS + b * CC + i] =
        (qrL[t] + u0L[t] * swS + usnL[t] * c0v) * inv + out_b[i];
  }

  // stage 2: A'[128,256] = Q @ V  (B^T = VT rows), + rank-1, -> bf16
  {
    const unsigned short* B2 = wsh + H_VHT + (size_t)(wc * 64) * CC;
    f32x4 acc[4][4] = {};
    for (int k0 = 0; k0 < 256; k0 += 32) {
      bf16x8 a[4], bb[4];
#pragma unroll
      for (int i = 0; i < 4; ++i) {
        a[i]  = *(const bf16x8*)(&Qh[wr * 64 + i * 16 + lm][lq * 8 + k0]);
        bb[i] = *(const bf16x8*)(B2 + (size_t)(i * 16 + lm) * CC + lq * 8 + k0);
      }
#pragma unroll
      for (int mi = 0; mi < 4; ++mi)
#pragma unroll
        for (int ni = 0; ni < 4; ++ni)
          acc[mi][ni] = __builtin_amdgcn_mfma_f32_16x16x32_bf16(a[mi], bb[ni], acc[mi][ni], 0, 0, 0);
    }
#pragma unroll
    for (int mi = 0; mi < 4; ++mi)
#pragma unroll
      for (int rr = 0; rr < 4; ++rr) {
        int rl = wr * 64 + mi * 16 + lq * 4 + rr;
        int gi = tm * 128 + rl;
        float u0i = u0L[rl];
        float usn = usnL[rl];
#pragma unroll
        for (int ni = 0; ni < 4; ++ni) {
          int gj = wc * 64 + ni * 16 + lm;
          float vv = (acc[mi][ni][rr] + u0i * vtsL[gj] + usn * tpbL[gj]) * inv;
          wsh[H_AH + (size_t)b * 65536 + (size_t)gi * CC + gj] = f2bf(vv);
        }
      }
  }
}

// ---- out = x + Ah @ x (via xT) + bias ----
__global__ __launch_bounds__(256) void k_out(const unsigned short* __restrict__ wsh,
                                             const float* __restrict__ wsf,
                                             const float* __restrict__ x,
                                             float* __restrict__ out) {
  int bid = blockIdx.x;
  int b = bid >> 6, r6 = bid & 63;
  int tm = r6 >> 5, tn = r6 & 31;
  int t = threadIdx.x, w = t >> 6, lane = t & 63;
  int wm = w >> 1, wn = w & 1;
  const unsigned short* A = wsh + H_AH + (size_t)b * 65536 + (size_t)(tm * 128 + wm * 64) * CC;
  const unsigned short* B = wsh + H_XT + ((size_t)b * NSP + tn * 128 + wn * 64) * CC;
  f32x4 acc[4][4] = {};
  wave_gemm_bt(A, CC, B, CC, 256, lane, acc);
  int lm = lane & 15, lq = lane >> 4;
  int rb = tm * 128 + wm * 64, cb = tn * 128 + wn * 64;
#pragma unroll
  for (int mi = 0; mi < 4; ++mi)
#pragma unroll
    for (int rr = 0; rr < 4; ++rr) {
      int row = rb + mi * 16 + lq * 4 + rr;
      float bi = wsf[F_BIAS + b * CC + row];
#pragma unroll
      for (int ni = 0; ni < 4; ++ni) {
        int col = cb + ni * 16 + lm;
        size_t off = ((size_t)b * CC + row) * NSP + col;
        out[off] = acc[mi][ni][rr] + x[off] + bi;
      }
    }
}

extern "C" void kernel_launch(void* const* d_in, const int* in_sizes, int n_in,
                              void* d_out, int out_size, void* d_ws, size_t ws_size,
                              hipStream_t stream) {
  const float* x       = (const float*)d_in[0];
  const float* g_w     = (const float*)d_in[1];
  const float* g_b     = (const float*)d_in[2];
  const float* theta_w = (const float*)d_in[3];
  const float* theta_b = (const float*)d_in[4];
  const float* phi_w   = (const float*)d_in[5];
  const float* phi_b   = (const float*)d_in[6];
  const float* out_w   = (const float*)d_in[7];
  const float* out_b   = (const float*)d_in[8];
  float* wsf = (float*)d_ws;
  unsigned short* wsh = (unsigned short*)(wsf + F_END);
  float* out = (float*)d_out;

  k_initprep<<<dim3(1537), dim3(256), 0, stream>>>(g_w, g_b, theta_w, theta_b,
                                                   phi_w, phi_b, out_w, x, wsf, wsh);
  k_gram<<<dim3(192), dim3(256), 0, stream>>>(wsh, wsf);
  k_gsum<<<dim3(256), dim3(256), 0, stream>>>(wsf, wsh);
  k_qa<<<dim3(8), dim3(512), 0, stream>>>(wsf, wsh, out_b, wsf);
  k_out<<<dim3(256), dim3(256), 0, stream>>>(wsh, wsf, x, out);
}

// Round 6
// 162.658 us; speedup vs baseline: 1.4221x; 1.0427x over previous
//
#include <hip/hip_runtime.h>
#include <hip/hip_bf16.h>

// Non-local block, algebraically collapsed to out_b = x_b + A'_b x_b + bias'_b,
// A'_b = (U G_b V + u0 (V^T s_b)^T + (U s_b + N u0) tpb^T)/N,  G_b = x_b x_b^T.
// 4 launches:
//  k1: gram(split-K=8, fp32->bf16 in-reg) + rowsum + XT-prep + small weights
//  k2: gsum (partials -> Gh bf16) + per-batch vectors (vts/usn/sw)
//  k3: qa  (Q = U@G in LDS, A' = Q@V + rank-1 + bias)
//  k4: out = x + A'@x + bias

#define CC   256
#define NSP  4096
#define NB   4
#define KSPLIT 8

typedef __attribute__((ext_vector_type(8))) short bf16x8;
typedef __attribute__((ext_vector_type(4))) float f32x4;

// fp32 region (float offsets)
#define F_P    0                         // [8][4][256][256] gram partials
#define F_U    2097152                   // [256][256]
#define F_VT   2162688                   // [256][256]  VT[i][j] = V[j][i]
#define F_S    2228224                   // [4][256]
#define F_U0   2229248                   // [256]
#define F_WTB  2229504                   // [256]
#define F_TPB  2229760                   // [256]
#define F_C0   2230016                   // [1] (+pad)
#define F_BIAS 2230032                   // [4][256]
#define F_VTS  2231056                   // [4][256]
#define F_USN  2232080                   // [4][256]
#define F_SW   2233104                   // [4] (+pad)
#define F_END  2233120
// bf16 region (ushort offsets from wsf + F_END)
#define H_XT   0                         // [4][4096][256]
#define H_GH   4194304                   // [4][256][256]
#define H_UH   4456448                   // [256][256]
#define H_VHT  4521984                   // [256][256]
#define H_AH   4587520                   // [4][256][256]

__device__ __forceinline__ unsigned short f2bf(float f) {
  __hip_bfloat16 h = __float2bfloat16(f);
  return __builtin_bit_cast(unsigned short, h);
}
__device__ __forceinline__ float bf2f(unsigned short u) {
  unsigned v = ((unsigned)u) << 16;
  return __builtin_bit_cast(float, v);
}
__device__ __forceinline__ uint4 pack8(const unsigned short* h) {
  uint4 u;
  u.x = (unsigned)h[0] | ((unsigned)h[1] << 16);
  u.y = (unsigned)h[2] | ((unsigned)h[3] << 16);
  u.z = (unsigned)h[4] | ((unsigned)h[5] << 16);
  u.w = (unsigned)h[6] | ((unsigned)h[7] << 16);
  return u;
}
// load 8 consecutive fp32, convert RNE -> bf16x8
__device__ __forceinline__ bf16x8 ld_cvt8(const float* __restrict__ p) {
  float4 lo = *(const float4*)p;
  float4 hi = *(const float4*)(p + 4);
  bf16x8 r;
  r[0] = (short)f2bf(lo.x); r[1] = (short)f2bf(lo.y);
  r[2] = (short)f2bf(lo.z); r[3] = (short)f2bf(lo.w);
  r[4] = (short)f2bf(hi.x); r[5] = (short)f2bf(hi.y);
  r[6] = (short)f2bf(hi.z); r[7] = (short)f2bf(hi.w);
  return r;
}

// Wave computes C[64x64] += A[64xK] * B^T[64xK] (bf16, row-major, K contiguous).
__device__ __forceinline__ void wave_gemm_bt(const unsigned short* __restrict__ A, int pitchA,
                                             const unsigned short* __restrict__ B, int pitchB,
                                             int K, int lane, f32x4 acc[4][4]) {
  int lm = lane & 15, lq = lane >> 4;
  const unsigned short* ap[4];
  const unsigned short* bp[4];
#pragma unroll
  for (int i = 0; i < 4; ++i) {
    ap[i] = A + (size_t)(i * 16 + lm) * pitchA + lq * 8;
    bp[i] = B + (size_t)(i * 16 + lm) * pitchB + lq * 8;
  }
  bf16x8 a0[4], b0[4];
#pragma unroll
  for (int i = 0; i < 4; ++i) {
    a0[i] = *(const bf16x8*)(ap[i]);
    b0[i] = *(const bf16x8*)(bp[i]);
  }
  for (int k = 32; k < K; k += 32) {
    bf16x8 a1[4], b1[4];
#pragma unroll
    for (int i = 0; i < 4; ++i) {
      a1[i] = *(const bf16x8*)(ap[i] + k);
      b1[i] = *(const bf16x8*)(bp[i] + k);
    }
#pragma unroll
    for (int mi = 0; mi < 4; ++mi)
#pragma unroll
      for (int ni = 0; ni < 4; ++ni)
        acc[mi][ni] = __builtin_amdgcn_mfma_f32_16x16x32_bf16(a0[mi], b0[ni], acc[mi][ni], 0, 0, 0);
#pragma unroll
    for (int i = 0; i < 4; ++i) { a0[i] = a1[i]; b0[i] = b1[i]; }
  }
#pragma unroll
  for (int mi = 0; mi < 4; ++mi)
#pragma unroll
    for (int ni = 0; ni < 4; ++ni)
      acc[mi][ni] = __builtin_amdgcn_mfma_f32_16x16x32_bf16(a0[mi], b0[ni], acc[mi][ni], 0, 0, 0);
}

// ---- k1: gram (fp32 src) + rowsum + XT-prep + smalls ----
__global__ __launch_bounds__(256) void k1(
    const float* __restrict__ g_w, const float* __restrict__ g_b,
    const float* __restrict__ theta_w, const float* __restrict__ theta_b,
    const float* __restrict__ phi_w, const float* __restrict__ phi_b,
    const float* __restrict__ out_w, const float* __restrict__ x,
    float* __restrict__ wsf, unsigned short* __restrict__ wsh) {
  __shared__ float T[64][65];
  int bid = blockIdx.x, t = threadIdx.x;
  if (bid < 128) {                   // gram split-K=8, direct from fp32 x
    int ks = bid & 7, t4 = (bid >> 3) & 3, b = bid >> 5;
    int tm = t4 >> 1, tn = t4 & 1;
    int w = t >> 6, lane = t & 63;
    int wm = w >> 1, wn = w & 1;
    int lm = lane & 15, lq = lane >> 4;
    const float* xb = x + (size_t)b * CC * NSP;
    int rb = tm * 128 + wm * 64, cb = tn * 128 + wn * 64;
    const float* ap[4];
    const float* bp[4];
#pragma unroll
    for (int i = 0; i < 4; ++i) {
      ap[i] = xb + (size_t)(rb + i * 16 + lm) * NSP + ks * 512 + lq * 8;
      bp[i] = xb + (size_t)(cb + i * 16 + lm) * NSP + ks * 512 + lq * 8;
    }
    f32x4 acc[4][4] = {};
    for (int k = 0; k < 512; k += 32) {
      bf16x8 a[4], bb[4];
#pragma unroll
      for (int i = 0; i < 4; ++i) {
        a[i]  = ld_cvt8(ap[i] + k);
        bb[i] = ld_cvt8(bp[i] + k);
      }
#pragma unroll
      for (int mi = 0; mi < 4; ++mi)
#pragma unroll
        for (int ni = 0; ni < 4; ++ni)
          acc[mi][ni] = __builtin_amdgcn_mfma_f32_16x16x32_bf16(a[mi], bb[ni], acc[mi][ni], 0, 0, 0);
    }
    float* P = wsf + F_P + (size_t)(ks * 4 + b) * 65536;
#pragma unroll
    for (int mi = 0; mi < 4; ++mi)
#pragma unroll
      for (int rr = 0; rr < 4; ++rr) {
        int row = rb + mi * 16 + lq * 4 + rr;
#pragma unroll
        for (int ni = 0; ni < 4; ++ni)
          P[row * CC + cb + ni * 16 + lm] = acc[mi][ni][rr];
      }
  } else if (bid < 192) {            // rowsums from fp32 x
    int rid = bid - 128;
    int b = rid >> 4, rg = rid & 15;
    int row = rg * 16 + (t >> 4), sub = t & 15;
    const float* xr = x + ((size_t)b * CC + row) * NSP + sub * 256;
    float s = 0.f;
    for (int q = 0; q < 256; q += 4) {
      float4 v = *(const float4*)(xr + q);
      s += v.x + v.y + v.z + v.w;
    }
    s += __shfl_down(s, 8);
    s += __shfl_down(s, 4);
    s += __shfl_down(s, 2);
    s += __shfl_down(s, 1);
    if (sub == 0) wsf[F_S + b * CC + row] = s;
  } else if (bid < 1216) {           // XT-prep: 64x64 transpose -> bf16 XT
    int pb = bid - 192;
    int nt = pb & 63, ct = (pb >> 6) & 3, b = pb >> 8;
    int c0 = ct * 64, n0 = nt * 64;
    int r = t >> 2, j = t & 3;
    const float* xr = x + ((size_t)b * CC + c0 + r) * NSP + n0 + j * 16;
    float4 f0 = *(const float4*)(xr);
    float4 f1 = *(const float4*)(xr + 4);
    float4 f2 = *(const float4*)(xr + 8);
    float4 f3 = *(const float4*)(xr + 12);
    *(float4*)&T[r][j * 16 + 0]  = f0;
    *(float4*)&T[r][j * 16 + 4]  = f1;
    *(float4*)&T[r][j * 16 + 8]  = f2;
    *(float4*)&T[r][j * 16 + 12] = f3;
    __syncthreads();
    int nr = t >> 2, j2 = t & 3;
    unsigned short o[16];
#pragma unroll
    for (int i = 0; i < 16; ++i) o[i] = f2bf(T[j2 * 16 + i][nr]);
    size_t to = ((size_t)b * NSP + n0 + nr) * CC + c0 + j2 * 16;
    *(uint4*)(wsh + H_XT + to)     = pack8(o);
    *(uint4*)(wsh + H_XT + to + 8) = pack8(o + 8);
  } else if (bid < 1472) {           // U[i][j] = sum_k out_w[i][k] g_w[k][j]
    int i = bid - 1216;
    float acc = 0.f;
    for (int k = 0; k < 128; ++k) acc = fmaf(out_w[i * 128 + k], g_w[k * CC + t], acc);
    wsf[F_U + i * CC + t] = acc;
    wsh[H_UH + i * CC + t] = f2bf(acc);
  } else if (bid < 1728) {           // VT[i][j] = V[j][i]
    int i = bid - 1472;
    float acc = 0.f;
    for (int k = 0; k < 128; ++k) acc = fmaf(theta_w[k * CC + i], phi_w[k * CC + t], acc);
    wsf[F_VT + i * CC + t] = acc;
    wsh[H_VHT + i * CC + t] = f2bf(acc);
  } else {                           // vectors + c0
    float a0 = 0.f, a1 = 0.f, a2 = 0.f;
    for (int k = 0; k < 128; ++k) {
      a0 = fmaf(out_w[t * 128 + k], g_b[k], a0);
      a1 = fmaf(phi_w[k * CC + t], theta_b[k], a1);
      a2 = fmaf(theta_w[k * CC + t], phi_b[k], a2);
    }
    wsf[F_U0 + t]  = a0;
    wsf[F_WTB + t] = a1;
    wsf[F_TPB + t] = a2;
    if (t == 0) {
      float c = 0.f;
      for (int k = 0; k < 128; ++k) c = fmaf(phi_b[k], theta_b[k], c);
      wsf[F_C0] = c;
    }
  }
}

// ---- k2: gsum (partials -> Gh bf16) + per-batch vectors ----
__global__ __launch_bounds__(256) void k2(float* __restrict__ wsf,
                                          unsigned short* __restrict__ wsh) {
  int bid = blockIdx.x, t = threadIdx.x;
  if (bid < 256) {
    int idx4 = (bid * 256 + t) * 4;    // over 262144 els
    float4 a = {0.f, 0.f, 0.f, 0.f};
#pragma unroll
    for (int ks = 0; ks < KSPLIT; ++ks) {
      float4 p = *(const float4*)(wsf + F_P + (size_t)ks * 262144 + idx4);
      a.x += p.x; a.y += p.y; a.z += p.z; a.w += p.w;
    }
    uint2 o;
    o.x = (unsigned)f2bf(a.x) | ((unsigned)f2bf(a.y) << 16);
    o.y = (unsigned)f2bf(a.z) | ((unsigned)f2bf(a.w) << 16);
    *(uint2*)(wsh + H_GH + idx4) = o;
  } else {                           // per-batch vectors: bid 256..259
    __shared__ float sL[256], red[256];
    int b = bid - 256;
    sL[t] = wsf[F_S + b * CC + t];
    __syncthreads();
    float vts = 0.f, usn = 0.f;
    const float* vr = wsf + F_VT + (size_t)t * CC;
    const float* ur = wsf + F_U + (size_t)t * CC;
    for (int k = 0; k < 256; ++k) {
      vts = fmaf(vr[k], sL[k], vts);
      usn = fmaf(ur[k], sL[k], usn);
    }
    usn += 4096.0f * wsf[F_U0 + t];
    wsf[F_VTS + b * CC + t] = vts;
    wsf[F_USN + b * CC + t] = usn;
    red[t] = sL[t] * wsf[F_WTB + t];
    __syncthreads();
    for (int st = 128; st > 0; st >>= 1) {
      if (t < st) red[t] += red[t + st];
      __syncthreads();
    }
    if (t == 0) wsf[F_SW + b] = red[0];
  }
}

// ---- k3: qa — Q = U@G (LDS), A' = Q@V + rank-1, bias ----
__global__ __launch_bounds__(256) void k3(const float* __restrict__ wsf,
                                          unsigned short* __restrict__ wsh,
                                          const float* __restrict__ out_b,
                                          float* __restrict__ wsfw) {
  __shared__ unsigned short Qh[64][264];
  __shared__ float vtsL[256], wtbL[256], tpbL[256], u0L[64], usnL[64];
  int bid = blockIdx.x;
  int b = bid >> 2, slab = bid & 3;
  int t = threadIdx.x, w = t >> 6, lane = t & 63;
  int lm = lane & 15, lq = lane >> 4;
  const float inv = 1.0f / 4096.0f;

  vtsL[t] = wsf[F_VTS + b * CC + t];
  wtbL[t] = wsf[F_WTB + t];
  tpbL[t] = wsf[F_TPB + t];
  if (t < 64) {
    u0L[t]  = wsf[F_U0 + slab * 64 + t];
    usnL[t] = wsf[F_USN + b * CC + slab * 64 + t];
  }
  __syncthreads();

  // stage 1: Q slab [64 x 256] = Uh rows @ Gh (G symmetric -> B^T = G rows)
  {
    const unsigned short* A1 = wsh + H_UH + (size_t)(slab * 64) * CC;
    const unsigned short* B1 = wsh + H_GH + (size_t)b * 65536 + (size_t)(w * 64) * CC;
    f32x4 acc[4][4] = {};
    wave_gemm_bt(A1, CC, B1, CC, 256, lane, acc);
#pragma unroll
    for (int mi = 0; mi < 4; ++mi)
#pragma unroll
      for (int rr = 0; rr < 4; ++rr) {
        int rl = mi * 16 + lq * 4 + rr;
#pragma unroll
        for (int ni = 0; ni < 4; ++ni)
          Qh[rl][w * 64 + ni * 16 + lm] = f2bf(acc[mi][ni][rr]);
      }
  }
  __syncthreads();
  float sw = wsf[F_SW + b];
  float c0v = wsf[F_C0];
  if (t < 64) {                      // bias rows for this slab
    float p = 0.f;
    for (int k = 0; k < 256; ++k) p = fmaf(bf2f(Qh[t][k]), wtbL[k], p);
    int i = slab * 64 + t;
    wsfw[F_BIAS + b * CC + i] =
        (p + u0L[t] * sw + usnL[t] * c0v) * inv + out_b[i];
  }

  // stage 2: A' slab = Q @ V + rank-1, -> bf16
  {
    const unsigned short* B2 = wsh + H_VHT + (size_t)(w * 64) * CC;
    f32x4 acc[4][4] = {};
    for (int k0 = 0; k0 < 256; k0 += 32) {
      bf16x8 a[4], bb[4];
#pragma unroll
      for (int i = 0; i < 4; ++i) {
        a[i]  = *(const bf16x8*)(&Qh[i * 16 + lm][lq * 8 + k0]);
        bb[i] = *(const bf16x8*)(B2 + (size_t)(i * 16 + lm) * CC + lq * 8 + k0);
      }
#pragma unroll
      for (int mi = 0; mi < 4; ++mi)
#pragma unroll
        for (int ni = 0; ni < 4; ++ni)
          acc[mi][ni] = __builtin_amdgcn_mfma_f32_16x16x32_bf16(a[mi], bb[ni], acc[mi][ni], 0, 0, 0);
    }
#pragma unroll
    for (int mi = 0; mi < 4; ++mi)
#pragma unroll
      for (int rr = 0; rr < 4; ++rr) {
        int rl = mi * 16 + lq * 4 + rr;
        int gi = slab * 64 + rl;
        float u0i = u0L[rl];
        float usn = usnL[rl];
#pragma unroll
        for (int ni = 0; ni < 4; ++ni) {
          int gj = w * 64 + ni * 16 + lm;
          float vv = (acc[mi][ni][rr] + u0i * vtsL[gj] + usn * tpbL[gj]) * inv;
          wsh[H_AH + (size_t)b * 65536 + (size_t)gi * CC + gj] = f2bf(vv);
        }
      }
  }
}

// ---- k4: out = x + Ah @ x (via xT) + bias ----
__global__ __launch_bounds__(256) void k4(const unsigned short* __restrict__ wsh,
                                          const float* __restrict__ wsf,
                                          const float* __restrict__ x,
                                          float* __restrict__ out) {
  int bid = blockIdx.x;
  int b = bid >> 6, r6 = bid & 63;
  int tm = r6 >> 5, tn = r6 & 31;
  int t = threadIdx.x, w = t >> 6, lane = t & 63;
  int wm = w >> 1, wn = w & 1;
  const unsigned short* A = wsh + H_AH + (size_t)b * 65536 + (size_t)(tm * 128 + wm * 64) * CC;
  const unsigned short* B = wsh + H_XT + ((size_t)b * NSP + tn * 128 + wn * 64) * CC;
  f32x4 acc[4][4] = {};
  wave_gemm_bt(A, CC, B, CC, 256, lane, acc);
  int lm = lane & 15, lq = lane >> 4;
  int rb = tm * 128 + wm * 64, cb = tn * 128 + wn * 64;
#pragma unroll
  for (int mi = 0; mi < 4; ++mi)
#pragma unroll
    for (int rr = 0; rr < 4; ++rr) {
      int row = rb + mi * 16 + lq * 4 + rr;
      float bi = wsf[F_BIAS + b * CC + row];
#pragma unroll
      for (int ni = 0; ni < 4; ++ni) {
        int col = cb + ni * 16 + lm;
        size_t off = ((size_t)b * CC + row) * NSP + col;
        out[off] = acc[mi][ni][rr] + x[off] + bi;
      }
    }
}

extern "C" void kernel_launch(void* const* d_in, const int* in_sizes, int n_in,
                              void* d_out, int out_size, void* d_ws, size_t ws_size,
                              hipStream_t stream) {
  const float* x       = (const float*)d_in[0];
  const float* g_w     = (const float*)d_in[1];
  const float* g_b     = (const float*)d_in[2];
  const float* theta_w = (const float*)d_in[3];
  const float* theta_b = (const float*)d_in[4];
  const float* phi_w   = (const float*)d_in[5];
  const float* phi_b   = (const float*)d_in[6];
  const float* out_w   = (const float*)d_in[7];
  const float* out_b   = (const float*)d_in[8];
  float* wsf = (float*)d_ws;
  unsigned short* wsh = (unsigned short*)(wsf + F_END);
  float* out = (float*)d_out;

  k1<<<dim3(1729), dim3(256), 0, stream>>>(g_w, g_b, theta_w, theta_b,
                                           phi_w, phi_b, out_w, x, wsf, wsh);
  k2<<<dim3(260), dim3(256), 0, stream>>>(wsf, wsh);
  k3<<<dim3(16), dim3(256), 0, stream>>>(wsf, wsh, out_b, wsf);
  k4<<<dim3(256), dim3(256), 0, stream>>>(wsh, wsf, x, out);
}